// Round 2
// baseline (2434.128 us; speedup 1.0000x reference)
//
#include <hip/hip_runtime.h>

#define T_STEPS 512
#define NTRAJ   4096
#define LAT     32
#define INPD    16
#define HID     20
#define CAT     48

__device__ __forceinline__ float fast_tanh(float x) {
    // tanh(x) = 1 - 2/(exp(2x)+1); inf-safe at both ends
    float e = __expf(2.0f * x);
    float r = __builtin_amdgcn_rcpf(e + 1.0f);
    return fmaf(-2.0f, r, 1.0f);
}
__device__ __forceinline__ float fast_sigmoid(float x) {
    float e = __expf(-x);
    return __builtin_amdgcn_rcpf(e + 1.0f);
}

// One wave = one trajectory. Zero LDS, zero barriers: all inter-layer
// broadcasts via ds_bpermute (__shfl). Lanes 0-31: output column c for gate u
// (and owner of y[c]); lanes 32-63: column c for gate r. x lives in lanes
// 32-47 of the operand pool registers.
__global__ __launch_bounds__(256) void rnn_fused(
    const float* __restrict__ data,
    const float* __restrict__ Wu1, const float* __restrict__ bu1,
    const float* __restrict__ Wu2, const float* __restrict__ bu2,
    const float* __restrict__ Wr1, const float* __restrict__ br1,
    const float* __restrict__ Wr2, const float* __restrict__ br2,
    const float* __restrict__ Wn1, const float* __restrict__ bn1,
    const float* __restrict__ Wn2, const float* __restrict__ bn2,
    float* __restrict__ out_yi, float* __restrict__ out_lat)
{
    const int tid  = threadIdx.x;
    const int w    = tid >> 6;
    const int lane = tid & 63;
    const int c    = lane & 31;   // output column
    const int g    = lane >> 5;   // 0 = u-side, 1 = r-side / K-half for n
    const int b    = (blockIdx.x << 2) + w;

    // ---- stage weights into registers ----
    float wa[CAT], wb[HID], wc[24], wd[HID];
    float ba, bb, bc, bd;
    {
        const float* W1 = g ? Wr1 : Wu1;
        const float* B1 = g ? br1 : bu1;
        const float* W2 = g ? Wr2 : Wu2;
        const float* B2 = g ? br2 : bu2;
        const bool real = (c < HID);
        #pragma unroll
        for (int k = 0; k < CAT; ++k) {
            int idx = real ? (k * HID + c) : 0;
            wa[k] = real ? W1[idx] : 0.0f;
        }
        ba = real ? B1[c] : 0.0f;
        #pragma unroll
        for (int k = 0; k < HID; ++k) wb[k] = W2[k * LAT + c];
        bb = B2[c];
        // n-gate layer 1: K split across halves; this half handles
        // operand slots g*24 + kk of the 48-wide cc vector.
        #pragma unroll
        for (int kk = 0; kk < 24; ++kk) {
            int idx = real ? ((g * 24 + kk) * HID + c) : 0;
            wc[kk] = real ? Wn1[idx] : 0.0f;
        }
        bc = (real && g == 0) ? bn1[c] : 0.0f;
        #pragma unroll
        for (int k = 0; k < HID; ++k) wd[k] = Wn2[k * LAT + c];
        bd = bn2[c];
    }

    // ---- x prefetch pipeline (2 deep) ----
    const float* xptr = data + (size_t)b * T_STEPS * INPD + (lane & 15);
    float x0 = xptr[0];
    float x1 = xptr[INPD];

    float y = 0.0f;               // lane c owns y[c] (valid on lanes 0-31)
    float* olat = out_lat + (size_t)b * T_STEPS * LAT + c;

    const int bsrc = lane & 32;   // phase-B shuffle base (own gate's hidden)
    const int csrc = g * 24;      // phase-C operand slot base

    for (int t = 0; t < T_STEPS; ++t) {
        // prefetch x(t+2)
        int tf = t + 2; tf = (tf < T_STEPS) ? tf : (T_STEPS - 1);
        float x2 = xptr[(size_t)tf * INPD];

        // ---- Phase A: layer-1 of u (half0) / r (half1), K=48 ----
        float pool = (lane < 32) ? y : x0;   // slots: [y(0..31) | x(32..47)]
        float a0 = ba, a1 = 0.0f, a2 = 0.0f, a3 = 0.0f;
        #pragma unroll
        for (int k = 0; k < CAT; k += 4) {
            a0 = fmaf(__shfl(pool, k + 0), wa[k + 0], a0);
            a1 = fmaf(__shfl(pool, k + 1), wa[k + 1], a1);
            a2 = fmaf(__shfl(pool, k + 2), wa[k + 2], a2);
            a3 = fmaf(__shfl(pool, k + 3), wa[k + 3], a3);
        }
        float h1 = fast_tanh((a0 + a1) + (a2 + a3));

        // ---- Phase B: layer-2 of own gate, K=20 ----
        float b0 = bb, b1 = 0.0f, b2 = 0.0f, b3 = 0.0f;
        #pragma unroll
        for (int k = 0; k < HID; k += 4) {
            b0 = fmaf(__shfl(h1, bsrc + k + 0), wb[k + 0], b0);
            b1 = fmaf(__shfl(h1, bsrc + k + 1), wb[k + 1], b1);
            b2 = fmaf(__shfl(h1, bsrc + k + 2), wb[k + 2], b2);
            b3 = fmaf(__shfl(h1, bsrc + k + 3), wb[k + 3], b3);
        }
        float gate = fast_sigmoid((b0 + b1) + (b2 + b3)); // u | r

        // ---- cc = [r*y | x] ----
        float rb  = __shfl(gate, 32 + c);    // r[c] to every lane
        float ccv = rb * y;                  // valid on lanes 0-31
        float pol2 = (lane < 32) ? ccv : x0;

        // ---- Phase C: layer-1 of n, K=48 split 24/24 across halves ----
        float c0 = bc, c1 = 0.0f, c2 = 0.0f, c3 = 0.0f;
        #pragma unroll
        for (int kk = 0; kk < 24; kk += 4) {
            c0 = fmaf(__shfl(pol2, csrc + kk + 0), wc[kk + 0], c0);
            c1 = fmaf(__shfl(pol2, csrc + kk + 1), wc[kk + 1], c1);
            c2 = fmaf(__shfl(pol2, csrc + kk + 2), wc[kk + 2], c2);
            c3 = fmaf(__shfl(pol2, csrc + kk + 3), wc[kk + 3], c3);
        }
        float cp = (c0 + c1) + (c2 + c3);
        float cs = cp + __shfl_xor(cp, 32);  // combine K-halves
        float hn = fast_tanh(cs);            // n-hidden[c], both halves

        // ---- Phase D: layer-2 of n, K=20 ----
        float d0 = bd, d1 = 0.0f, d2 = 0.0f, d3 = 0.0f;
        #pragma unroll
        for (int k = 0; k < HID; k += 4) {
            d0 = fmaf(__shfl(hn, k + 0), wd[k + 0], d0);
            d1 = fmaf(__shfl(hn, k + 1), wd[k + 1], d1);
            d2 = fmaf(__shfl(hn, k + 2), wd[k + 2], d2);
            d3 = fmaf(__shfl(hn, k + 3), wd[k + 3], d3);
        }
        float n = fast_tanh((d0 + d1) + (d2 + d3));

        // ---- combine: y' = (1-u)*n + u*y  (u = gate on half0) ----
        float ny = fmaf(gate, y - n, n);
        y = ny;                              // half1's y is unused garbage
        if (lane < 32) olat[(size_t)t * LAT] = ny;

        x0 = x1; x1 = x2;
    }

    if (lane < 32) out_yi[(size_t)b * LAT + c] = y;
}

extern "C" void kernel_launch(void* const* d_in, const int* in_sizes, int n_in,
                              void* d_out, int out_size, void* d_ws, size_t ws_size,
                              hipStream_t stream) {
    const float* data = (const float*)d_in[0];
    const float* Wu1 = (const float*)d_in[2];
    const float* bu1 = (const float*)d_in[3];
    const float* Wu2 = (const float*)d_in[4];
    const float* bu2 = (const float*)d_in[5];
    const float* Wr1 = (const float*)d_in[6];
    const float* br1 = (const float*)d_in[7];
    const float* Wr2 = (const float*)d_in[8];
    const float* br2 = (const float*)d_in[9];
    const float* Wn1 = (const float*)d_in[10];
    const float* bn1 = (const float*)d_in[11];
    const float* Wn2 = (const float*)d_in[12];
    const float* bn2 = (const float*)d_in[13];

    float* out_yi  = (float*)d_out;
    float* out_lat = out_yi + (size_t)NTRAJ * LAT;

    rnn_fused<<<NTRAJ / 4, 256, 0, stream>>>(
        data, Wu1, bu1, Wu2, bu2, Wr1, br1, Wr2, br2, Wn1, bn1, Wn2, bn2,
        out_yi, out_lat);
}

// Round 3
// 1123.153 us; speedup vs baseline: 2.1672x; 2.1672x over previous
//
#include <hip/hip_runtime.h>

#define T_STEPS 512
#define NTRAJ   4096
#define LAT     32
#define INPD    16
#define HID     20
#define CAT     48

__device__ __forceinline__ float fast_tanh(float x) {
    float e = __expf(2.0f * x);
    float r = __builtin_amdgcn_rcpf(e + 1.0f);
    return fmaf(-2.0f, r, 1.0f);
}
__device__ __forceinline__ float fast_sigmoid(float x) {
    float e = __expf(-x);
    return __builtin_amdgcn_rcpf(e + 1.0f);
}

// Read v rotated right by I within each 16-lane row (DPP row_ror:I).
// Lane l reads lane (l & ~15) | ((l - I) & 15). I==0 is identity.
template<int I> __device__ __forceinline__ float ror16(float v) {
    if constexpr (I == 0) {
        return v;
    } else {
        int r = __builtin_amdgcn_update_dpp(0, __float_as_int(v),
                                            0x120 | I, 0xF, 0xF, true);
        return __int_as_float(r);
    }
}

#define REP16(M) M(0) M(1) M(2) M(3) M(4) M(5) M(6) M(7) \
                 M(8) M(9) M(10) M(11) M(12) M(13) M(14) M(15)

// One wave = one trajectory. All matvecs are systolic DPP-ring reads on the
// VALU pipe; per step only 5 ds ops (__shfl_xor) and 2 VMEM ops.
// Lane layout: c = lane&31 (column), g = lane>>5 (0=u-gate, 1=r-gate),
// p = (lane>>4)&1 (row parity -> which 16-wide slot block this row sees).
__global__ __launch_bounds__(256, 2) void rnn_fused(
    const float* __restrict__ data,
    const float* __restrict__ Wu1, const float* __restrict__ bu1,
    const float* __restrict__ Wu2, const float* __restrict__ bu2,
    const float* __restrict__ Wr1, const float* __restrict__ br1,
    const float* __restrict__ Wr2, const float* __restrict__ br2,
    const float* __restrict__ Wn1, const float* __restrict__ bn1,
    const float* __restrict__ Wn2, const float* __restrict__ bn2,
    float* __restrict__ out_yi, float* __restrict__ out_lat)
{
    const int tid  = threadIdx.x;
    const int w    = tid >> 6;
    const int lane = tid & 63;
    const int c    = lane & 31;
    const int g    = lane >> 5;
    const int p    = (lane >> 4) & 1;
    const int b    = (blockIdx.x << 2) + w;

    const float* W1 = g ? Wr1 : Wu1;
    const float* B1 = g ? br1 : bu1;
    const float* W2 = g ? Wr2 : Wu2;
    const float* B2 = g ? br2 : bu2;
    const bool realc = (c < HID);

    // Stationary per-lane weights, indexed by rotation step i.
    // At iter i this lane's ring reads deliver:
    //   nat ring  -> slot sa = 16*p     + ((c-i)&15)
    //   swap ring -> slot sb = 16*(1-p) + ((c-i)&15)
    //   x ring    -> slot sx = 32       + ((c-i)&15)
    float wa_a[16], wa_b[16], wa_x[16], wb_a[16], wb_b[16];
    float wc_a[16], wc_b[16], wc_x[16], wd_a[16], wd_b[16];
    #pragma unroll
    for (int i = 0; i < 16; ++i) {
        int s  = (c - i) & 15;
        int sa = 16 * p + s;
        int sb = 16 * (1 - p) + s;
        int sx = 32 + s;
        wa_a[i] = realc ? W1[sa * HID + c] : 0.0f;
        wa_b[i] = realc ? W1[sb * HID + c] : 0.0f;
        wa_x[i] = realc ? W1[sx * HID + c] : 0.0f;
        wb_a[i] = (sa < HID) ? W2[sa * LAT + c] : 0.0f;
        wb_b[i] = (sb < HID) ? W2[sb * LAT + c] : 0.0f;
        wc_a[i] = realc ? Wn1[sa * HID + c] : 0.0f;
        wc_b[i] = realc ? Wn1[sb * HID + c] : 0.0f;
        wc_x[i] = realc ? Wn1[sx * HID + c] : 0.0f;
        wd_a[i] = (sa < HID) ? Wn2[sa * LAT + c] : 0.0f;
        wd_b[i] = (sb < HID) ? Wn2[sb * LAT + c] : 0.0f;
    }
    const float ba = realc ? B1[c] : 0.0f;
    const float bb = B2[c];
    const float bc = realc ? bn1[c] : 0.0f;
    const float bd = bn2[c];

    // x ring: lane l holds x[l&15]; 2-step prefetch pipeline.
    const float* xptr = data + (size_t)b * T_STEPS * INPD + (lane & 15);
    float x0 = xptr[0];
    float x1 = xptr[INPD];

    float y  = 0.0f;   // y[c], maintained on ALL 64 lanes
    float y2 = 0.0f;   // y[c^16]
    float* olat = out_lat + (size_t)b * T_STEPS * LAT + c;

    for (int t = 0; t < T_STEPS; ++t) {
        int tf = t + 2; tf = (tf < T_STEPS) ? tf : (T_STEPS - 1);
        float xn = xptr[(size_t)tf * INPD];

        // ---- Phase A: layer-1 of own gate, K=48 = y(32) + x(16) ----
        float acc[4] = {ba, 0.f, 0.f, 0.f};
        #define PA(i) \
            acc[(i)&3]     = fmaf(ror16<(i)>(y),  wa_a[(i)], acc[(i)&3]); \
            acc[((i)+1)&3] = fmaf(ror16<(i)>(y2), wa_b[(i)], acc[((i)+1)&3]); \
            acc[((i)+2)&3] = fmaf(ror16<(i)>(x0), wa_x[(i)], acc[((i)+2)&3]);
        REP16(PA)
        #undef PA
        float h1 = fast_tanh((acc[0] + acc[1]) + (acc[2] + acc[3]));
        float h2 = __shfl_xor(h1, 16);

        // ---- Phase B: layer-2 of own gate, K=20 (12 zero-weight slots) ----
        float bcc[4] = {bb, 0.f, 0.f, 0.f};
        #define PB(i) \
            bcc[(i)&3]     = fmaf(ror16<(i)>(h1), wb_a[(i)], bcc[(i)&3]); \
            bcc[((i)+1)&3] = fmaf(ror16<(i)>(h2), wb_b[(i)], bcc[((i)+1)&3]);
        REP16(PB)
        #undef PB
        float gate = fast_sigmoid((bcc[0] + bcc[1]) + (bcc[2] + bcc[3]));

        float exch  = __shfl_xor(gate, 32);   // other gate's value for col c
        float u_all = g ? exch : gate;
        float r_all = g ? gate : exch;
        float ry    = r_all * y;              // cc slot c, all lanes
        float ry2   = __shfl_xor(ry, 16);

        // ---- Phase C: layer-1 of n, K=48 = ry(32) + x(16), both halves ----
        float ccc[4] = {bc, 0.f, 0.f, 0.f};
        #define PC(i) \
            ccc[(i)&3]     = fmaf(ror16<(i)>(ry),  wc_a[(i)], ccc[(i)&3]); \
            ccc[((i)+1)&3] = fmaf(ror16<(i)>(ry2), wc_b[(i)], ccc[((i)+1)&3]); \
            ccc[((i)+2)&3] = fmaf(ror16<(i)>(x0),  wc_x[(i)], ccc[((i)+2)&3]);
        REP16(PC)
        #undef PC
        float hn  = fast_tanh((ccc[0] + ccc[1]) + (ccc[2] + ccc[3]));
        float hn2 = __shfl_xor(hn, 16);

        // ---- Phase D: layer-2 of n, K=20 ----
        float dcc[4] = {bd, 0.f, 0.f, 0.f};
        #define PD(i) \
            dcc[(i)&3]     = fmaf(ror16<(i)>(hn),  wd_a[(i)], dcc[(i)&3]); \
            dcc[((i)+1)&3] = fmaf(ror16<(i)>(hn2), wd_b[(i)], dcc[((i)+1)&3]);
        REP16(PD)
        #undef PD
        float n = fast_tanh((dcc[0] + dcc[1]) + (dcc[2] + dcc[3]));

        // ---- y' = (1-u)*n + u*y, maintained on all lanes ----
        float ny = fmaf(u_all, y - n, n);
        y  = ny;
        y2 = __shfl_xor(ny, 16);
        if (lane < 32) olat[(size_t)t * LAT] = ny;

        x0 = x1; x1 = xn;
    }

    if (lane < 32) out_yi[(size_t)b * LAT + c] = y;
}

extern "C" void kernel_launch(void* const* d_in, const int* in_sizes, int n_in,
                              void* d_out, int out_size, void* d_ws, size_t ws_size,
                              hipStream_t stream) {
    const float* data = (const float*)d_in[0];
    const float* Wu1 = (const float*)d_in[2];
    const float* bu1 = (const float*)d_in[3];
    const float* Wu2 = (const float*)d_in[4];
    const float* bu2 = (const float*)d_in[5];
    const float* Wr1 = (const float*)d_in[6];
    const float* br1 = (const float*)d_in[7];
    const float* Wr2 = (const float*)d_in[8];
    const float* br2 = (const float*)d_in[9];
    const float* Wn1 = (const float*)d_in[10];
    const float* bn1 = (const float*)d_in[11];
    const float* Wn2 = (const float*)d_in[12];
    const float* bn2 = (const float*)d_in[13];

    float* out_yi  = (float*)d_out;
    float* out_lat = out_yi + (size_t)NTRAJ * LAT;

    rnn_fused<<<NTRAJ / 4, 256, 0, stream>>>(
        data, Wu1, bu1, Wu2, bu2, Wr1, br1, Wr2, br2, Wn1, bn1, Wn2, bn2,
        out_yi, out_lat);
}